// Round 13
// baseline (45.213 us; speedup 1.0000x reference)
//
#include <hip/hip_runtime.h>
#include <stdint.h>
#include <math.h>

#define WAVE 64
#define TOPK 16

// ---------- agent-scope atomics (coherence point; no fences) ----------
__device__ __forceinline__ uint32_t aload_u32(const uint32_t* p) {
    return __hip_atomic_load(p, __ATOMIC_RELAXED, __HIP_MEMORY_SCOPE_AGENT);
}
__device__ __forceinline__ float aload_f32(const float* p) {
    return __hip_atomic_load(p, __ATOMIC_RELAXED, __HIP_MEMORY_SCOPE_AGENT);
}
__device__ __forceinline__ void astore_f32(float* p, float v) {
    __hip_atomic_store(p, v, __ATOMIC_RELAXED, __HIP_MEMORY_SCOPE_AGENT);
}
__device__ __forceinline__ void astore_rel_u32(uint32_t* p, uint32_t v) {
    __hip_atomic_store(p, v, __ATOMIC_RELEASE, __HIP_MEMORY_SCOPE_AGENT);
}

// Monotone bijection fp32 -> uint32 (order-preserving).
__device__ __forceinline__ uint32_t f2s(float f) {
    uint32_t u = __float_as_uint(f);
    return u ^ (uint32_t)(((int32_t)u >> 31) | 0x80000000u);
}
__device__ __forceinline__ uint32_t umax32(uint32_t a, uint32_t b) { return a > b ? a : b; }
__device__ __forceinline__ uint32_t umin32(uint32_t a, uint32_t b) { return a < b ? a : b; }

template <int CTRL, int RMASK>
__device__ __forceinline__ uint32_t dppmax(uint32_t m) {
    uint32_t r = (uint32_t)__builtin_amdgcn_update_dpp((int)m, (int)m, CTRL, RMASK, 0xF, false);
    return umax32(m, r);
}
// Wave-wide (64-lane) max, pure VALU (DPP) + one readlane. Returns uniform value.
__device__ __forceinline__ uint32_t wave_umax(uint32_t m) {
    m = dppmax<0x121, 0xF>(m);  // row_ror:1
    m = dppmax<0x122, 0xF>(m);  // row_ror:2
    m = dppmax<0x124, 0xF>(m);  // row_ror:4
    m = dppmax<0x128, 0xF>(m);  // row_ror:8  -> row max everywhere
    m = dppmax<0x142, 0xA>(m);  // row_bcast:15 -> rows 1,3
    m = dppmax<0x143, 0xC>(m);  // row_bcast:31 -> rows 2,3; lane 63 = global
    return (uint32_t)__builtin_amdgcn_readlane((int)m, 63);
}

template <int VPL>
__device__ __forceinline__ uint32_t gpos(int j, int lane) {
    if constexpr (VPL == 1) return (uint32_t)lane;
    else return (uint32_t)((j >> 2) * (WAVE * 4) + lane * 4 + (j & 3));
}

#define CE_(x, y) { const uint32_t h_ = umax32(x, y), l_ = umin32(x, y); (x) = h_; (y) = l_; }

// ---------- generic top-16 selection (R4-verbatim) for P=64/256 ----------
template <int P>
__device__ __forceinline__ void topk_select(const float* __restrict__ crow,
                                            const int lane,
                                            uint32_t* __restrict__ idx) {
    constexpr int VPL = P / WAVE;
    constexpr uint32_t IMASK = (uint32_t)(P - 1);

    uint32_t k[VPL];
    if constexpr (VPL == 1) {
        k[0] = (f2s(crow[lane]) & ~IMASK) | (uint32_t)lane;
    } else {
#pragma unroll
        for (int c = 0; c < VPL / 4; ++c) {
            float4 f4 = *reinterpret_cast<const float4*>(crow + c * (WAVE * 4) + lane * 4);
            const uint32_t b = (uint32_t)(c * (WAVE * 4) + lane * 4);
            k[c * 4 + 0] = (f2s(f4.x) & ~IMASK) | (b + 0u);
            k[c * 4 + 1] = (f2s(f4.y) & ~IMASK) | (b + 1u);
            k[c * 4 + 2] = (f2s(f4.z) & ~IMASK) | (b + 2u);
            k[c * 4 + 3] = (f2s(f4.w) & ~IMASK) | (b + 3u);
        }
#pragma unroll
        for (int size = 2; size <= VPL; size <<= 1) {
#pragma unroll
            for (int stride = size >> 1; stride > 0; stride >>= 1) {
#pragma unroll
                for (int i = 0; i < VPL; ++i) {
                    const int j = i ^ stride;
                    if (j > i) {
                        if ((i & size) == 0) { CE_(k[i], k[j]); }
                        else                 { CE_(k[j], k[i]); }
                    }
                }
            }
        }
    }

    uint32_t q16 = 0;
#pragma unroll
    for (int t = 0; t < TOPK; ++t) {
        const uint32_t K = wave_umax(k[0]);
        idx[t] = K & IMASK;
        if (t == TOPK - 1) q16 = K & ~IMASK;
        const bool won = (k[0] == K);
#pragma unroll
        for (int j = 0; j < VPL - 1; ++j) k[j] = won ? k[j + 1] : k[j];
        k[VPL - 1] = won ? 0u : k[VPL - 1];
    }
    const uint32_t k17 = wave_umax(k[0]);

    if ((k17 & ~IMASK) == q16) {
        // EXACT fallback (rare): lexicographic (value, index) iterative extract.
        uint32_t v[VPL];
        if constexpr (VPL == 1) {
            v[0] = f2s(crow[lane]);
        } else {
#pragma unroll
            for (int c = 0; c < VPL / 4; ++c) {
                float4 f4 = *reinterpret_cast<const float4*>(crow + c * (WAVE * 4) + lane * 4);
                v[c * 4 + 0] = f2s(f4.x);
                v[c * 4 + 1] = f2s(f4.y);
                v[c * 4 + 2] = f2s(f4.z);
                v[c * 4 + 3] = f2s(f4.w);
            }
        }
#pragma unroll
        for (int t = 0; t < TOPK; ++t) {
            uint32_t m = v[0];
            int li = 0;
#pragma unroll
            for (int j = 1; j < VPL; ++j) {
                bool c = v[j] >= m;
                m = c ? v[j] : m;
                li = c ? j : li;
            }
            uint32_t gi = gpos<VPL>(li, lane);
            const uint32_t mygi = gi;
            uint32_t mm = m;
#pragma unroll
            for (int off = 32; off > 0; off >>= 1) {
                uint32_t om = (uint32_t)__shfl_xor((int)mm, off);
                uint32_t og = (uint32_t)__shfl_xor((int)gi, off);
                bool c = (om > mm) || (om == mm && og > gi);
                mm = c ? om : mm;
                gi = c ? og : gi;
            }
            idx[t] = gi;
            const bool won = (mygi == gi) && (m == mm);
#pragma unroll
            for (int j = 0; j < VPL; ++j) {
                if (won && j == li) v[j] = 0u;
            }
        }
    }
}

// ---------- specialized P=1024: top-4 sorted head + 12-entry reserve ----------
// (R11-validated) Winner sequence identical to full-sort version.
__device__ __forceinline__ void topk_select_1024(const float* __restrict__ crow,
                                                 const int lane,
                                                 uint32_t* __restrict__ idx) {
    constexpr uint32_t IMASK = 1023u;

    uint32_t k[16];
#pragma unroll
    for (int c = 0; c < 4; ++c) {
        float4 f4 = *reinterpret_cast<const float4*>(crow + c * (WAVE * 4) + lane * 4);
        const uint32_t b = (uint32_t)(c * (WAVE * 4) + lane * 4);
        k[c * 4 + 0] = (f2s(f4.x) & ~IMASK) | (b + 0u);
        k[c * 4 + 1] = (f2s(f4.y) & ~IMASK) | (b + 1u);
        k[c * 4 + 2] = (f2s(f4.z) & ~IMASK) | (b + 2u);
        k[c * 4 + 3] = (f2s(f4.w) & ~IMASK) | (b + 3u);
    }
#pragma unroll
    for (int c = 0; c < 4; ++c) {
        CE_(k[4 * c + 0], k[4 * c + 1]); CE_(k[4 * c + 2], k[4 * c + 3]);
        CE_(k[4 * c + 0], k[4 * c + 2]); CE_(k[4 * c + 1], k[4 * c + 3]);
        CE_(k[4 * c + 1], k[4 * c + 2]);
    }
    uint32_t h[4], g[4], t[4], r[12];
#pragma unroll
    for (int i = 0; i < 4; ++i) { h[i] = umax32(k[i], k[7 - i]); r[i] = umin32(k[i], k[7 - i]); }
    CE_(h[0], h[2]); CE_(h[1], h[3]); CE_(h[0], h[1]); CE_(h[2], h[3]);
#pragma unroll
    for (int i = 0; i < 4; ++i) { g[i] = umax32(k[8 + i], k[15 - i]); r[4 + i] = umin32(k[8 + i], k[15 - i]); }
    CE_(g[0], g[2]); CE_(g[1], g[3]); CE_(g[0], g[1]); CE_(g[2], g[3]);
#pragma unroll
    for (int i = 0; i < 4; ++i) { t[i] = umax32(h[i], g[3 - i]); r[8 + i] = umin32(h[i], g[3 - i]); }
    CE_(t[0], t[2]); CE_(t[1], t[3]); CE_(t[0], t[1]); CE_(t[2], t[3]);

    uint32_t q16 = 0;
#pragma unroll
    for (int tt = 0; tt < TOPK; ++tt) {
        if (__any(t[0] == 0u)) {
            const bool need = (t[0] == 0u);
            uint32_t rm = r[0];
#pragma unroll
            for (int j = 1; j < 12; ++j) rm = umax32(rm, r[j]);
#pragma unroll
            for (int j = 0; j < 12; ++j) r[j] = (need && r[j] == rm) ? 0u : r[j];
            t[0] = need ? rm : t[0];
        }
        const uint32_t K = wave_umax(t[0]);
        idx[tt] = K & IMASK;
        if (tt == TOPK - 1) q16 = K & ~IMASK;
        const bool won = (t[0] == K);
        t[0] = won ? t[1] : t[0];
        t[1] = won ? t[2] : t[1];
        t[2] = won ? t[3] : t[2];
        t[3] = won ? 0u : t[3];
    }
    if (__any(t[0] == 0u)) {
        const bool need = (t[0] == 0u);
        uint32_t rm = r[0];
#pragma unroll
        for (int j = 1; j < 12; ++j) rm = umax32(rm, r[j]);
        t[0] = need ? rm : t[0];
    }
    const uint32_t k17 = wave_umax(t[0]);

    if ((k17 & ~IMASK) == q16) {
        uint32_t v[16];
#pragma unroll
        for (int c = 0; c < 4; ++c) {
            float4 f4 = *reinterpret_cast<const float4*>(crow + c * (WAVE * 4) + lane * 4);
            v[c * 4 + 0] = f2s(f4.x);
            v[c * 4 + 1] = f2s(f4.y);
            v[c * 4 + 2] = f2s(f4.z);
            v[c * 4 + 3] = f2s(f4.w);
        }
#pragma unroll
        for (int tt = 0; tt < TOPK; ++tt) {
            uint32_t m = v[0];
            int li = 0;
#pragma unroll
            for (int j = 1; j < 16; ++j) {
                bool c = v[j] >= m;
                m = c ? v[j] : m;
                li = c ? j : li;
            }
            uint32_t gi = gpos<16>(li, lane);
            const uint32_t mygi = gi;
            uint32_t mm = m;
#pragma unroll
            for (int off = 32; off > 0; off >>= 1) {
                uint32_t om = (uint32_t)__shfl_xor((int)mm, off);
                uint32_t og = (uint32_t)__shfl_xor((int)gi, off);
                bool c = (om > mm) || (om == mm && og > gi);
                mm = c ? om : mm;
                gi = c ? og : gi;
            }
            idx[tt] = gi;
            const bool won = (mygi == gi) && (m == mm);
#pragma unroll
            for (int j = 0; j < 16; ++j) {
                if (won && j == li) v[j] = 0u;
            }
        }
    }
}

// ---------- fused k1+k2 (one node): producers + flags, consumers poll ----------
// Blocks 0..63 (4 waves each) produce the 256 e2 rows FIRST, then every block's
// 4 waves do one conn2 row each. Consumer selection (~400 ops) runs before the
// flag wait, hiding producer latency. e2 is read via agent atomic loads (64KB
// buffer; 4MB total gather traffic). e1 written normally: the k3 kernel
// boundary provides dispatch-level acquire/release across XCDs.
__global__ void __launch_bounds__(256)
fused12_kernel(const float* __restrict__ conn2,
               const float* __restrict__ conn3,
               const float* __restrict__ root,
               uint32_t* __restrict__ fe2,   // [256] flags (memset 0 each call)
               float* __restrict__ e2,       // [256*64]
               float* __restrict__ e1,       // [1024*64]
               int n1) {
    const int lane = threadIdx.x & (WAVE - 1);
    const int wib = threadIdx.x >> 6;
    const int row = blockIdx.x * 4 + wib;      // k2 row (0..1023)

    // ---- producer: e2 row (blocks 0-63) ----
    if (blockIdx.x < 64) {
        const int prow = row;                  // e2 row 0..255
        const float* __restrict__ c3 = conn3 + prow * 64;
        uint32_t pidx[TOPK];
        topk_select<64>(c3, lane, pidx);
        float pv[TOPK];
#pragma unroll
        for (int t = 0; t < TOPK; ++t) pv[t] = c3[pidx[t]];
        const float pv0 = pv[0];
        float ps = 0.f, pa = 0.f;
#pragma unroll
        for (int t = 0; t < TOPK; ++t) {
            const float w = __expf(pv[t] - pv0);
            ps += w;
            pa = fmaf(w, root[pidx[t] * 64u + (uint32_t)lane], pa);
        }
        astore_f32(&e2[prow * 64 + lane], pa / ps);
        asm volatile("s_waitcnt vmcnt(0)" ::: "memory");   // drain this wave's stores
        if (lane == 0) astore_rel_u32(&fe2[prow], 1u);
    }

    // ---- consumer: k2 row (all 256 blocks) ----
    const float* __restrict__ crow = conn2 + (long)row * 256;
    uint32_t idx[TOPK];
    topk_select<256>(crow, lane, idx);
    float vsel[TOPK];
#pragma unroll
    for (int t = 0; t < TOPK; ++t) vsel[t] = crow[idx[t]];

    // wait for all 256 e2 flags (4 per lane); typically already set
    {
        int spins = 0;
        for (;;) {
            uint32_t ok = aload_u32(fe2 + lane) & aload_u32(fe2 + lane + 64) &
                          aload_u32(fe2 + lane + 128) & aload_u32(fe2 + lane + 192);
            if (__all(ok == 1u)) break;
            __builtin_amdgcn_s_sleep(8);
            if (++spins > (1 << 20)) break;  // safety: fail visibly, not hang
        }
    }

    const float v0 = vsel[0];
    float ssum = 0.f, acc = 0.f;
#pragma unroll
    for (int t = 0; t < TOPK; ++t) {
        const float w = __expf(vsel[t] - v0);
        ssum += w;
        acc = fmaf(w, aload_f32(&e2[idx[t] * 64u + (uint32_t)lane]), acc);
    }
    e1[(long)row * 64 + lane] = acc / ssum;
}

// ---------- leaves (k3): R11-validated, unchanged ----------
#define K3_BLOCKS 1024

__global__ void leaf_kernel(const int* __restrict__ ids,
                            const float* __restrict__ conn1,
                            const float* __restrict__ e1,
                            float* __restrict__ out,
                            int batch) {
    const int lane = threadIdx.x & (WAVE - 1);
    const int wid = blockIdx.x * (blockDim.x >> 6) + (threadIdx.x >> 6);
    const int nw = K3_BLOCKS * 4;

    for (int row = wid; row < batch; row += nw) {
        const float* __restrict__ crow = conn1 + (long)ids[row] * 1024;

        uint32_t idx[TOPK];
        topk_select_1024(crow, lane, idx);

        float vsel[TOPK];
#pragma unroll
        for (int t = 0; t < TOPK; ++t) vsel[t] = crow[idx[t]];
        const float v0 = vsel[0];
        float ssum = 0.f, acc = 0.f;
#pragma unroll
        for (int t = 0; t < TOPK; ++t) {
            const float w = __expf(vsel[t] - v0);
            ssum += w;
            acc = fmaf(w, e1[idx[t] * 64u + (uint32_t)lane], acc);
        }
        out[(long)row * 64 + lane] = acc / ssum;
    }
}

extern "C" void kernel_launch(void* const* d_in, const int* in_sizes, int n_in,
                              void* d_out, int out_size, void* d_ws, size_t ws_size,
                              hipStream_t stream) {
    const int* ids = (const int*)d_in[0];          // [8192] int32
    const float* conn1 = (const float*)d_in[1];    // [200000, 1024]
    const float* conn2 = (const float*)d_in[2];    // [1024, 256]
    const float* conn3 = (const float*)d_in[3];    // [256, 64]
    const float* root = (const float*)d_in[4];     // [64, 64]
    float* out = (float*)d_out;                    // [8192, 64]

    const int batch = in_sizes[0];                 // 8192
    const int n1 = 1024;

    uint32_t* fe2 = (uint32_t*)d_ws;               // [256] flags
    float* e2 = (float*)((char*)d_ws + 1024);      // [256, 64]
    float* e1 = e2 + (size_t)256 * 64;             // [1024, 64]

    // Zero flags (1 KB DMA fill node; much cheaper than a kernel node).
    hipMemsetAsync(fe2, 0, 256 * sizeof(uint32_t), stream);

    // Node 1: fused levels 2+1 (256 blocks)
    fused12_kernel<<<dim3(256), dim3(256), 0, stream>>>(conn2, conn3, root, fe2, e2, e1, n1);

    // Node 2: leaves
    leaf_kernel<<<dim3(K3_BLOCKS), dim3(256), 0, stream>>>(ids, conn1, e1, out, batch);
}

// Round 14
// 45.161 us; speedup vs baseline: 1.0011x; 1.0011x over previous
//
#include <hip/hip_runtime.h>
#include <stdint.h>
#include <math.h>

#define WAVE 64
#define TOPK 16

// Monotone bijection fp32 -> uint32 (order-preserving).
__device__ __forceinline__ uint32_t f2s(float f) {
    uint32_t u = __float_as_uint(f);
    return u ^ (uint32_t)(((int32_t)u >> 31) | 0x80000000u);
}
__device__ __forceinline__ uint32_t umax32(uint32_t a, uint32_t b) { return a > b ? a : b; }
__device__ __forceinline__ uint32_t umin32(uint32_t a, uint32_t b) { return a < b ? a : b; }

template <int CTRL, int RMASK>
__device__ __forceinline__ uint32_t dppmax(uint32_t m) {
    uint32_t r = (uint32_t)__builtin_amdgcn_update_dpp((int)m, (int)m, CTRL, RMASK, 0xF, false);
    return umax32(m, r);
}
// Wave-wide (64-lane) max, pure VALU (DPP) + one readlane. Returns uniform value.
__device__ __forceinline__ uint32_t wave_umax(uint32_t m) {
    m = dppmax<0x121, 0xF>(m);  // row_ror:1
    m = dppmax<0x122, 0xF>(m);  // row_ror:2
    m = dppmax<0x124, 0xF>(m);  // row_ror:4
    m = dppmax<0x128, 0xF>(m);  // row_ror:8  -> row max everywhere
    m = dppmax<0x142, 0xA>(m);  // row_bcast:15 -> rows 1,3
    m = dppmax<0x143, 0xC>(m);  // row_bcast:31 -> rows 2,3; lane 63 = global
    return (uint32_t)__builtin_amdgcn_readlane((int)m, 63);
}

template <int VPL>
__device__ __forceinline__ uint32_t gpos(int j, int lane) {
    if constexpr (VPL == 1) return (uint32_t)lane;
    else return (uint32_t)((j >> 2) * (WAVE * 4) + lane * 4 + (j & 3));
}

#define CE_(x, y) { const uint32_t h_ = umax32(x, y), l_ = umin32(x, y); (x) = h_; (y) = l_; }

// ---------- generic top-16 selection (R4-verbatim) for P=64/256 ----------
template <int P>
__device__ __forceinline__ void topk_select(const float* __restrict__ crow,
                                            const int lane,
                                            uint32_t* __restrict__ idx) {
    constexpr int VPL = P / WAVE;
    constexpr uint32_t IMASK = (uint32_t)(P - 1);

    uint32_t k[VPL];
    if constexpr (VPL == 1) {
        k[0] = (f2s(crow[lane]) & ~IMASK) | (uint32_t)lane;
    } else {
#pragma unroll
        for (int c = 0; c < VPL / 4; ++c) {
            float4 f4 = *reinterpret_cast<const float4*>(crow + c * (WAVE * 4) + lane * 4);
            const uint32_t b = (uint32_t)(c * (WAVE * 4) + lane * 4);
            k[c * 4 + 0] = (f2s(f4.x) & ~IMASK) | (b + 0u);
            k[c * 4 + 1] = (f2s(f4.y) & ~IMASK) | (b + 1u);
            k[c * 4 + 2] = (f2s(f4.z) & ~IMASK) | (b + 2u);
            k[c * 4 + 3] = (f2s(f4.w) & ~IMASK) | (b + 3u);
        }
#pragma unroll
        for (int size = 2; size <= VPL; size <<= 1) {
#pragma unroll
            for (int stride = size >> 1; stride > 0; stride >>= 1) {
#pragma unroll
                for (int i = 0; i < VPL; ++i) {
                    const int j = i ^ stride;
                    if (j > i) {
                        if ((i & size) == 0) { CE_(k[i], k[j]); }
                        else                 { CE_(k[j], k[i]); }
                    }
                }
            }
        }
    }

    uint32_t q16 = 0;
#pragma unroll
    for (int t = 0; t < TOPK; ++t) {
        const uint32_t K = wave_umax(k[0]);
        idx[t] = K & IMASK;
        if (t == TOPK - 1) q16 = K & ~IMASK;
        const bool won = (k[0] == K);
#pragma unroll
        for (int j = 0; j < VPL - 1; ++j) k[j] = won ? k[j + 1] : k[j];
        k[VPL - 1] = won ? 0u : k[VPL - 1];
    }
    const uint32_t k17 = wave_umax(k[0]);

    if ((k17 & ~IMASK) == q16) {
        // EXACT fallback (rare): lexicographic (value, index) iterative extract.
        uint32_t v[VPL];
        if constexpr (VPL == 1) {
            v[0] = f2s(crow[lane]);
        } else {
#pragma unroll
            for (int c = 0; c < VPL / 4; ++c) {
                float4 f4 = *reinterpret_cast<const float4*>(crow + c * (WAVE * 4) + lane * 4);
                v[c * 4 + 0] = f2s(f4.x);
                v[c * 4 + 1] = f2s(f4.y);
                v[c * 4 + 2] = f2s(f4.z);
                v[c * 4 + 3] = f2s(f4.w);
            }
        }
#pragma unroll
        for (int t = 0; t < TOPK; ++t) {
            uint32_t m = v[0];
            int li = 0;
#pragma unroll
            for (int j = 1; j < VPL; ++j) {
                bool c = v[j] >= m;
                m = c ? v[j] : m;
                li = c ? j : li;
            }
            uint32_t gi = gpos<VPL>(li, lane);
            const uint32_t mygi = gi;
            uint32_t mm = m;
#pragma unroll
            for (int off = 32; off > 0; off >>= 1) {
                uint32_t om = (uint32_t)__shfl_xor((int)mm, off);
                uint32_t og = (uint32_t)__shfl_xor((int)gi, off);
                bool c = (om > mm) || (om == mm && og > gi);
                mm = c ? om : mm;
                gi = c ? og : gi;
            }
            idx[t] = gi;
            const bool won = (mygi == gi) && (m == mm);
#pragma unroll
            for (int j = 0; j < VPL; ++j) {
                if (won && j == li) v[j] = 0u;
            }
        }
    }
}

// ---------- specialized P=1024: top-4 sorted head + 12-entry reserve ----------
// (R11-validated) Winner sequence identical to full-sort version.
__device__ __forceinline__ void topk_select_1024(const float* __restrict__ crow,
                                                 const int lane,
                                                 uint32_t* __restrict__ idx) {
    constexpr uint32_t IMASK = 1023u;

    uint32_t k[16];
#pragma unroll
    for (int c = 0; c < 4; ++c) {
        float4 f4 = *reinterpret_cast<const float4*>(crow + c * (WAVE * 4) + lane * 4);
        const uint32_t b = (uint32_t)(c * (WAVE * 4) + lane * 4);
        k[c * 4 + 0] = (f2s(f4.x) & ~IMASK) | (b + 0u);
        k[c * 4 + 1] = (f2s(f4.y) & ~IMASK) | (b + 1u);
        k[c * 4 + 2] = (f2s(f4.z) & ~IMASK) | (b + 2u);
        k[c * 4 + 3] = (f2s(f4.w) & ~IMASK) | (b + 3u);
    }
#pragma unroll
    for (int c = 0; c < 4; ++c) {
        CE_(k[4 * c + 0], k[4 * c + 1]); CE_(k[4 * c + 2], k[4 * c + 3]);
        CE_(k[4 * c + 0], k[4 * c + 2]); CE_(k[4 * c + 1], k[4 * c + 3]);
        CE_(k[4 * c + 1], k[4 * c + 2]);
    }
    uint32_t h[4], g[4], t[4], r[12];
#pragma unroll
    for (int i = 0; i < 4; ++i) { h[i] = umax32(k[i], k[7 - i]); r[i] = umin32(k[i], k[7 - i]); }
    CE_(h[0], h[2]); CE_(h[1], h[3]); CE_(h[0], h[1]); CE_(h[2], h[3]);
#pragma unroll
    for (int i = 0; i < 4; ++i) { g[i] = umax32(k[8 + i], k[15 - i]); r[4 + i] = umin32(k[8 + i], k[15 - i]); }
    CE_(g[0], g[2]); CE_(g[1], g[3]); CE_(g[0], g[1]); CE_(g[2], g[3]);
#pragma unroll
    for (int i = 0; i < 4; ++i) { t[i] = umax32(h[i], g[3 - i]); r[8 + i] = umin32(h[i], g[3 - i]); }
    CE_(t[0], t[2]); CE_(t[1], t[3]); CE_(t[0], t[1]); CE_(t[2], t[3]);

    uint32_t q16 = 0;
#pragma unroll
    for (int tt = 0; tt < TOPK; ++tt) {
        if (__any(t[0] == 0u)) {
            const bool need = (t[0] == 0u);
            uint32_t rm = r[0];
#pragma unroll
            for (int j = 1; j < 12; ++j) rm = umax32(rm, r[j]);
#pragma unroll
            for (int j = 0; j < 12; ++j) r[j] = (need && r[j] == rm) ? 0u : r[j];
            t[0] = need ? rm : t[0];
        }
        const uint32_t K = wave_umax(t[0]);
        idx[tt] = K & IMASK;
        if (tt == TOPK - 1) q16 = K & ~IMASK;
        const bool won = (t[0] == K);
        t[0] = won ? t[1] : t[0];
        t[1] = won ? t[2] : t[1];
        t[2] = won ? t[3] : t[2];
        t[3] = won ? 0u : t[3];
    }
    if (__any(t[0] == 0u)) {
        const bool need = (t[0] == 0u);
        uint32_t rm = r[0];
#pragma unroll
        for (int j = 1; j < 12; ++j) rm = umax32(rm, r[j]);
        t[0] = need ? rm : t[0];
    }
    const uint32_t k17 = wave_umax(t[0]);

    if ((k17 & ~IMASK) == q16) {
        uint32_t v[16];
#pragma unroll
        for (int c = 0; c < 4; ++c) {
            float4 f4 = *reinterpret_cast<const float4*>(crow + c * (WAVE * 4) + lane * 4);
            v[c * 4 + 0] = f2s(f4.x);
            v[c * 4 + 1] = f2s(f4.y);
            v[c * 4 + 2] = f2s(f4.z);
            v[c * 4 + 3] = f2s(f4.w);
        }
#pragma unroll
        for (int tt = 0; tt < TOPK; ++tt) {
            uint32_t m = v[0];
            int li = 0;
#pragma unroll
            for (int j = 1; j < 16; ++j) {
                bool c = v[j] >= m;
                m = c ? v[j] : m;
                li = c ? j : li;
            }
            uint32_t gi = gpos<16>(li, lane);
            const uint32_t mygi = gi;
            uint32_t mm = m;
#pragma unroll
            for (int off = 32; off > 0; off >>= 1) {
                uint32_t om = (uint32_t)__shfl_xor((int)mm, off);
                uint32_t og = (uint32_t)__shfl_xor((int)gi, off);
                bool c = (om > mm) || (om == mm && og > gi);
                mm = c ? om : mm;
                gi = c ? og : gi;
            }
            idx[tt] = gi;
            const bool won = (mygi == gi) && (m == mm);
#pragma unroll
            for (int j = 0; j < 16; ++j) {
                if (won && j == li) v[j] = 0u;
            }
        }
    }
}

// ---------- e2 row value (R4-verbatim math), ONE compiled body (noinline) ----
// Called 16x from the k2 path; noinline prevents the R9 register blowup.
__device__ __attribute__((noinline)) float e2val(const float* __restrict__ c3,
                                                 const float* __restrict__ root,
                                                 const int lane) {
    uint32_t idx[TOPK];
    topk_select<64>(c3, lane, idx);
    float vsel[TOPK];
#pragma unroll
    for (int t = 0; t < TOPK; ++t) vsel[t] = c3[idx[t]];
    const float v0 = vsel[0];
    float ssum = 0.f, acc = 0.f;
#pragma unroll
    for (int t = 0; t < TOPK; ++t) {
        const float w = __expf(vsel[t] - v0);
        ssum += w;
        acc = fmaf(w, root[idx[t] * 64u + (uint32_t)lane], acc);
    }
    return acc / ssum;
}

// ---------- Node A: k2 rows (on-demand e2) ∥ leaf selection ----------
#define K2_BLOCKS 256
#define LEAF_BLOCKS 768

__global__ void __launch_bounds__(256, 2)
nodeA_kernel(const int* __restrict__ ids,
             const float* __restrict__ conn1,
             const float* __restrict__ conn2,
             const float* __restrict__ conn3,
             const float* __restrict__ root,
             float* __restrict__ e1,       // [1024*64]
             float* __restrict__ wbuf,     // [8192*16]
             uint32_t* __restrict__ ibuf,  // [8192*16]
             float* __restrict__ sbuf,     // [8192]
             int batch) {
    const int lane = threadIdx.x & (WAVE - 1);
    const int wib = threadIdx.x >> 6;
    const int bid = blockIdx.x;

    if (bid < K2_BLOCKS) {
        // ---- k2 row: select on conn2, e2 values computed on demand ----
        const int row = bid * 4 + wib;  // 0..1023
        const float* __restrict__ crow = conn2 + (long)row * 256;
        uint32_t idx[TOPK];
        topk_select<256>(crow, lane, idx);
        float vsel[TOPK];
#pragma unroll
        for (int t = 0; t < TOPK; ++t) vsel[t] = crow[idx[t]];
        const float v0 = vsel[0];
        float w[TOPK];
        float ssum = 0.f;
#pragma unroll
        for (int t = 0; t < TOPK; ++t) {
            w[t] = __expf(vsel[t] - v0);
            ssum += w[t];
        }
        float acc = 0.f;
#pragma unroll
        for (int t = 0; t < TOPK; ++t) {
            acc = fmaf(w[t], e2val(conn3 + idx[t] * 64u, root, lane), acc);
        }
        e1[(long)row * 64 + lane] = acc / ssum;
    } else {
        // ---- leaf selection: store w[16], idx[16], ssum; finish in node B ----
        const int wid = (bid - K2_BLOCKS) * 4 + wib;
        for (int row = wid; row < batch; row += LEAF_BLOCKS * 4) {
            const float* __restrict__ crow = conn1 + (long)ids[row] * 1024;
            uint32_t idx[TOPK];
            topk_select_1024(crow, lane, idx);
            float vsel[TOPK];
#pragma unroll
            for (int t = 0; t < TOPK; ++t) vsel[t] = crow[idx[t]];
            const float v0 = vsel[0];
            float w[TOPK];
            float ssum = 0.f;
#pragma unroll
            for (int t = 0; t < TOPK; ++t) {
                w[t] = __expf(vsel[t] - v0);
                ssum += w[t];
            }
            // route w[lane]/idx[lane] to lanes 0..15 via static cndmask chain
            float myw = w[0];
            uint32_t myi = idx[0];
#pragma unroll
            for (int t = 1; t < TOPK; ++t) {
                myw = (lane == t) ? w[t] : myw;
                myi = (lane == t) ? idx[t] : myi;
            }
            if (lane < TOPK) {
                wbuf[(long)row * 16 + lane] = myw;
                ibuf[(long)row * 16 + lane] = myi;
            }
            if (lane == 0) sbuf[row] = ssum;
        }
    }
}

// ---------- Node B: leaf finish (gather e1, weighted sum, write out) --------
#define B_BLOCKS 1024

__global__ void __launch_bounds__(256, 4)
nodeB_kernel(const float* __restrict__ e1,
             const float* __restrict__ wbuf,
             const uint32_t* __restrict__ ibuf,
             const float* __restrict__ sbuf,
             float* __restrict__ out,
             int batch) {
    const int lane = threadIdx.x & (WAVE - 1);
    const int wid = blockIdx.x * (blockDim.x >> 6) + (threadIdx.x >> 6);

    for (int row = wid; row < batch; row += B_BLOCKS * 4) {
        const float4* wp = reinterpret_cast<const float4*>(wbuf + (long)row * 16);
        const float4 w0 = wp[0], w1 = wp[1], w2 = wp[2], w3 = wp[3];
        const uint4* ip = reinterpret_cast<const uint4*>(ibuf + (long)row * 16);
        const uint4 i0 = ip[0], i1 = ip[1], i2 = ip[2], i3 = ip[3];

        float acc = 0.f;
        acc = fmaf(w0.x, e1[i0.x * 64u + (uint32_t)lane], acc);
        acc = fmaf(w0.y, e1[i0.y * 64u + (uint32_t)lane], acc);
        acc = fmaf(w0.z, e1[i0.z * 64u + (uint32_t)lane], acc);
        acc = fmaf(w0.w, e1[i0.w * 64u + (uint32_t)lane], acc);
        acc = fmaf(w1.x, e1[i1.x * 64u + (uint32_t)lane], acc);
        acc = fmaf(w1.y, e1[i1.y * 64u + (uint32_t)lane], acc);
        acc = fmaf(w1.z, e1[i1.z * 64u + (uint32_t)lane], acc);
        acc = fmaf(w1.w, e1[i1.w * 64u + (uint32_t)lane], acc);
        acc = fmaf(w2.x, e1[i2.x * 64u + (uint32_t)lane], acc);
        acc = fmaf(w2.y, e1[i2.y * 64u + (uint32_t)lane], acc);
        acc = fmaf(w2.z, e1[i2.z * 64u + (uint32_t)lane], acc);
        acc = fmaf(w2.w, e1[i2.w * 64u + (uint32_t)lane], acc);
        acc = fmaf(w3.x, e1[i3.x * 64u + (uint32_t)lane], acc);
        acc = fmaf(w3.y, e1[i3.y * 64u + (uint32_t)lane], acc);
        acc = fmaf(w3.z, e1[i3.z * 64u + (uint32_t)lane], acc);
        acc = fmaf(w3.w, e1[i3.w * 64u + (uint32_t)lane], acc);

        out[(long)row * 64 + lane] = acc / sbuf[row];
    }
}

extern "C" void kernel_launch(void* const* d_in, const int* in_sizes, int n_in,
                              void* d_out, int out_size, void* d_ws, size_t ws_size,
                              hipStream_t stream) {
    const int* ids = (const int*)d_in[0];          // [8192] int32
    const float* conn1 = (const float*)d_in[1];    // [200000, 1024]
    const float* conn2 = (const float*)d_in[2];    // [1024, 256]
    const float* conn3 = (const float*)d_in[3];    // [256, 64]
    const float* root = (const float*)d_in[4];     // [64, 64]
    float* out = (float*)d_out;                    // [8192, 64]

    const int batch = in_sizes[0];                 // 8192

    float* e1 = (float*)d_ws;                      // [1024*64]  256 KB
    float* wbuf = e1 + 1024 * 64;                  // [8192*16]  512 KB
    uint32_t* ibuf = (uint32_t*)(wbuf + 8192 * 16);// [8192*16]  512 KB
    float* sbuf = (float*)(ibuf + 8192 * 16);      // [8192]      32 KB

    // Node A: k2 (on-demand e2, no k1 kernel) ∥ leaf selection
    nodeA_kernel<<<dim3(K2_BLOCKS + LEAF_BLOCKS), dim3(256), 0, stream>>>(
        ids, conn1, conn2, conn3, root, e1, wbuf, ibuf, sbuf, batch);

    // Node B: leaf finish
    nodeB_kernel<<<dim3(B_BLOCKS), dim3(256), 0, stream>>>(
        e1, wbuf, ibuf, sbuf, out, batch);
}